// Round 13
// baseline (55.944 us; speedup 1.0000x reference)
//
#include <hip/hip_runtime.h>
#include <math.h>

// Problem constants (fixed by harness)
#define NN   128
#define TT   1024
#define SS   1024
#define H1D  512
#define H2D  128
#define OUTD 8
#define TCH  16     // t-chunks (TC=64 each, 2 halves of 32 per block)
#define TC   64
#define SPT  8      // s-values per thread (dual depth-3 rotation chains)
#define KQN  8      // layer-1 split-K chunks

// ws layout in floats (~19.7 MB)
#define OFF_RI   0                         // partials [ch][n][s] float2 (re,im)
#define OFF_FREQ (TCH*NN*SS*2)             // 4194304: freq [n][s]
#define OFF_P1   (OFF_FREQ + NN*SS)        // 4325376: P1 [8 kq][128 n][512 j]
#define OFF_H1   (OFF_P1 + KQN*NN*H1D)     // 4849664: h1 [n][512]
#define OFF_H2   (OFF_H1 + NN*H1D)         // 4915200: h2 [n][128] (end 4931584)

__device__ __forceinline__ float cos_rev(float r) { return __builtin_amdgcn_cosf(r); } // cos(2*pi*r)
__device__ __forceinline__ float sin_rev(float r) { return __builtin_amdgcn_sinf(r); } // sin(2*pi*r)

__device__ __forceinline__ float wave_sum(float v) {
#pragma unroll
    for (int off = 32; off > 0; off >>= 1) v += __shfl_xor(v, off, 64);
    return v;
}

// ---------------------------------------------------------------------------
// Kernel 1: partial NUDFT v3. Diagnosis from R12: v2 was latency-bound —
// ~356 cy/iter serial chain (LDS 120 + frac 20 + sincos + 4 rotates) vs
// ~80 cy issue, at only 4 waves/SIMD (~22% issue busy). v3: (a) TCH=16 ->
// 8192 waves = 8 waves/SIMD (forced by __launch_bounds__(256,8), ~50 VGPR);
// (b) TWO independent t-point chains per iteration (i, i+16) hide each
// other's latency. Math per point is bit-identical to R8/R12's v2.
// ---------------------------------------------------------------------------
__global__ __launch_bounds__(256, 8) void k_nudft(const float* __restrict__ inp,
                                                  float* __restrict__ ws) {
    const int tc  = blockIdx.x;    // 0..15
    const int n   = blockIdx.y;    // 0..127
    const int tid = threadIdx.x;
    const int th  = tid >> 7;      // t-half 0/1 (32 t each)
    const int sl  = tid & 127;     // s-lane

    __shared__ float4 shA[TC];     // {frac(day), x, cos(2pi d), sin(2pi d)}
    __shared__ float2 shB[TC];     // {cos(2pi 4d), sin(2pi 4d)}
    __shared__ float2 red[SPT][128];
    if (tid < TC) {
        const float* p = inp + (size_t)(n * TT + tc * TC + tid) * 3;
        const float x  = p[0];
        const float d  = p[2];
        const float df = d - floorf(d);            // exact for |d| < 2^23
        float r4 = 4.0f * df;
        r4 -= floorf(r4);
        shA[tid] = make_float4(df, x, cos_rev(df), sin_rev(df));
        shB[tid] = make_float2(cos_rev(r4), sin_rev(r4));
    }
    __syncthreads();

    const float s0f = (float)(sl * SPT);
    float2 acc[SPT];
#pragma unroll
    for (int q = 0; q < SPT; ++q) acc[q] = make_float2(0.f, 0.f);

#pragma unroll 2
    for (int i = 0; i < 16; ++i) {
        const int i1 = th * 32 + i;
        const int i2 = i1 + 16;
        const float4 v1 = shA[i1];  const float2 w1 = shB[i1];
        const float4 v2 = shA[i2];  const float2 w2 = shB[i2];

        // --- point 1 chain ---
        const float p1   = s0f * v1.x;
        const float plo1 = fmaf(s0f, v1.x, -p1);
        const float r1   = (p1 - floorf(p1)) + plo1;
        const float c1  = cos_rev(r1);
        const float sn1 = sin_rev(r1);
        float cB1 = fmaf(-sn1, w1.y, c1 * w1.x);
        float sB1 = fmaf( c1,  w1.y, sn1 * w1.x);
        float cA1 = c1, sA1 = sn1;
        // --- point 2 chain (independent; compiler interleaves) ---
        const float p2   = s0f * v2.x;
        const float plo2 = fmaf(s0f, v2.x, -p2);
        const float r2   = (p2 - floorf(p2)) + plo2;
        const float c2  = cos_rev(r2);
        const float sn2 = sin_rev(r2);
        float cB2 = fmaf(-sn2, w2.y, c2 * w2.x);
        float sB2 = fmaf( c2,  w2.y, sn2 * w2.x);
        float cA2 = c2, sA2 = sn2;

        acc[0].x = fmaf(v1.y, cA1, acc[0].x); acc[0].y = fmaf(v1.y, sA1, acc[0].y);
        acc[4].x = fmaf(v1.y, cB1, acc[4].x); acc[4].y = fmaf(v1.y, sB1, acc[4].y);
        acc[0].x = fmaf(v2.y, cA2, acc[0].x); acc[0].y = fmaf(v2.y, sA2, acc[0].y);
        acc[4].x = fmaf(v2.y, cB2, acc[4].x); acc[4].y = fmaf(v2.y, sB2, acc[4].y);
#pragma unroll
        for (int q = 1; q < 4; ++q) {
            const float cA1n = fmaf(-sA1, v1.w, cA1 * v1.z);
            const float sA1n = fmaf( cA1, v1.w, sA1 * v1.z);
            const float cB1n = fmaf(-sB1, v1.w, cB1 * v1.z);
            const float sB1n = fmaf( cB1, v1.w, sB1 * v1.z);
            const float cA2n = fmaf(-sA2, v2.w, cA2 * v2.z);
            const float sA2n = fmaf( cA2, v2.w, sA2 * v2.z);
            const float cB2n = fmaf(-sB2, v2.w, cB2 * v2.z);
            const float sB2n = fmaf( cB2, v2.w, sB2 * v2.z);
            cA1 = cA1n; sA1 = sA1n; cB1 = cB1n; sB1 = sB1n;
            cA2 = cA2n; sA2 = sA2n; cB2 = cB2n; sB2 = sB2n;
            acc[q].x     = fmaf(v1.y, cA1, acc[q].x);
            acc[q].y     = fmaf(v1.y, sA1, acc[q].y);
            acc[q + 4].x = fmaf(v1.y, cB1, acc[q + 4].x);
            acc[q + 4].y = fmaf(v1.y, sB1, acc[q + 4].y);
            acc[q].x     = fmaf(v2.y, cA2, acc[q].x);
            acc[q].y     = fmaf(v2.y, sA2, acc[q].y);
            acc[q + 4].x = fmaf(v2.y, cB2, acc[q + 4].x);
            acc[q + 4].y = fmaf(v2.y, sB2, acc[q + 4].y);
        }
    }

    if (th == 1) {
#pragma unroll
        for (int q = 0; q < SPT; ++q) red[q][sl] = acc[q];
    }
    __syncthreads();
    if (th == 0) {
        float4* RI = (float4*)(ws + OFF_RI) +
                     ((((size_t)(tc * NN + n)) * SS + sl * SPT) >> 1);
#pragma unroll
        for (int q = 0; q < SPT / 2; ++q) {
            const float2 r0 = red[2*q][sl], r1 = red[2*q+1][sl];
            RI[q] = make_float4(acc[2*q].x + r0.x, acc[2*q].y + r0.y,
                                acc[2*q+1].x + r1.x, acc[2*q+1].y + r1.y);
        }
    }
}

// ---------------------------------------------------------------------------
// Kernel 2: combine t-chunk partials -> frequential (R12 verbatim; TCH=16)
// ---------------------------------------------------------------------------
__global__ __launch_bounds__(256) void k_combine1(float* __restrict__ ws) {
    const int idx = blockIdx.x * 256 + threadIdx.x;   // = n*SS + s
    const float2* P = (const float2*)(ws + OFF_RI);
    float re = 0.f, im = 0.f;
#pragma unroll
    for (int ch = 0; ch < TCH; ++ch) {
        const float2 v = P[(size_t)ch * (NN * SS) + idx];
        re += v.x; im += v.y;
    }
    ws[OFF_FREQ + idx] = sqrtf(fmaf(re, re, im * im));
}

// ---------------------------------------------------------------------------
// Kernel 3: layer-1 split-K partial GEMM (R12 verbatim)
// ---------------------------------------------------------------------------
__global__ __launch_bounds__(256) void k_l1p(const float* __restrict__ W1,
                                             float* __restrict__ ws) {
    const int kq = blockIdx.x;   // 0..7   k-chunk of 128
    const int jq = blockIdx.y;   // 0..3   j-chunk of 128
    const int nb = blockIdx.z;   // 0..15  n-chunk of 8
    const int tid = threadIdx.x;

    __shared__ float4 Al[8][32];  // 8 n-rows x 128 k (as float4)
    const float4* FQ = (const float4*)(ws + OFF_FREQ);
    {
        const int row = tid >> 5, c4 = tid & 31;
        Al[row][c4] = FQ[(nb * 8 + row) * 256 + kq * 32 + c4];
    }
    __syncthreads();

    const int jl = tid & 127, ng = tid >> 7;
    const int j = jq * 128 + jl;
    const float4* W1v = (const float4*)W1;
    float a0 = 0.f, a1 = 0.f, a2 = 0.f, a3 = 0.f;
#pragma unroll 4
    for (int k4 = 0; k4 < 32; ++k4) {
        const float4 w  = W1v[(size_t)j * 256 + kq * 32 + k4];
        const float4 x0 = Al[ng * 4 + 0][k4];
        const float4 x1 = Al[ng * 4 + 1][k4];
        const float4 x2 = Al[ng * 4 + 2][k4];
        const float4 x3 = Al[ng * 4 + 3][k4];
        a0 = fmaf(x0.x, w.x, fmaf(x0.y, w.y, fmaf(x0.z, w.z, fmaf(x0.w, w.w, a0))));
        a1 = fmaf(x1.x, w.x, fmaf(x1.y, w.y, fmaf(x1.z, w.z, fmaf(x1.w, w.w, a1))));
        a2 = fmaf(x2.x, w.x, fmaf(x2.y, w.y, fmaf(x2.z, w.z, fmaf(x2.w, w.w, a2))));
        a3 = fmaf(x3.x, w.x, fmaf(x3.y, w.y, fmaf(x3.z, w.z, fmaf(x3.w, w.w, a3))));
    }
    float* P1 = ws + OFF_P1;
    const float acc[4] = {a0, a1, a2, a3};
#pragma unroll
    for (int i = 0; i < 4; ++i)
        P1[((size_t)(kq * NN + nb * 8 + ng * 4 + i)) * H1D + j] = acc[i];
}

// ---------------------------------------------------------------------------
// Kernel 4: combine layer-1 partials + bias + sigmoid -> h1 (R12 verbatim)
// ---------------------------------------------------------------------------
__global__ __launch_bounds__(256) void k_l1c(const float* __restrict__ b1,
                                             float* __restrict__ ws) {
    const int tid = blockIdx.x * 256 + threadIdx.x;   // = n*H1D + j
    const int j = tid & (H1D - 1);
    float s = b1[j];
#pragma unroll
    for (int kq = 0; kq < KQN; ++kq) s += ws[OFF_P1 + (size_t)kq * (NN * H1D) + tid];
    ws[OFF_H1 + tid] = 1.0f / (1.0f + __expf(-s));
}

// ---------------------------------------------------------------------------
// Kernel 5: layer-2, one wave per (n,j) (R12 verbatim)
// ---------------------------------------------------------------------------
__global__ __launch_bounds__(256) void k_l2(const float* __restrict__ W2,
                                            const float* __restrict__ b2,
                                            float* __restrict__ ws) {
    const int task = blockIdx.x * 4 + (threadIdx.x >> 6);   // 0..16383
    const int lane = threadIdx.x & 63;
    const int n = task >> 7, j = task & 127;

    const float4* W2v = (const float4*)W2 + (size_t)j * 128;
    const float4* H1v = (const float4*)(ws + OFF_H1) + (size_t)n * 128;
    const float4 wa = W2v[lane],      wb = W2v[64 + lane];
    const float4 ha = H1v[lane],      hb = H1v[64 + lane];
    float a = fmaf(wa.x, ha.x, fmaf(wa.y, ha.y, fmaf(wa.z, ha.z, wa.w * ha.w)));
    a = fmaf(wb.x, hb.x, fmaf(wb.y, hb.y, fmaf(wb.z, hb.z, fmaf(wb.w, hb.w, a))));
    a = wave_sum(a);
    if (lane == 0)
        ws[OFF_H2 + (size_t)n * H2D + j] = 1.0f / (1.0f + __expf(-(a + b2[j])));
}

// ---------------------------------------------------------------------------
// Kernel 6: layer-3, one wave per (n,j) (R12 verbatim)
// ---------------------------------------------------------------------------
__global__ __launch_bounds__(256) void k_l3(const float* __restrict__ W3,
                                            const float* __restrict__ b3,
                                            const float* __restrict__ ws,
                                            float* __restrict__ out) {
    const int task = blockIdx.x * 4 + (threadIdx.x >> 6);   // 0..1023
    const int lane = threadIdx.x & 63;
    const int n = task >> 3, j = task & 7;

    const float2 w = ((const float2*)W3)[j * 64 + lane];
    const float2 h = ((const float2*)(ws + OFF_H2 + (size_t)n * H2D))[lane];
    float a = fmaf(w.x, h.x, w.y * h.y);
    a = wave_sum(a);
    if (lane == 0) out[n * OUTD + j] = a + b3[j];
}

extern "C" void kernel_launch(void* const* d_in, const int* in_sizes, int n_in,
                              void* d_out, int out_size, void* d_ws, size_t ws_size,
                              hipStream_t stream) {
    (void)in_sizes; (void)n_in; (void)out_size; (void)ws_size;
    const float* inp = (const float*)d_in[0];
    const float* W1  = (const float*)d_in[1];
    const float* b1  = (const float*)d_in[2];
    const float* W2  = (const float*)d_in[3];
    const float* b2  = (const float*)d_in[4];
    const float* W3  = (const float*)d_in[5];
    const float* b3  = (const float*)d_in[6];
    float* out = (float*)d_out;
    float* ws  = (float*)d_ws;

    k_nudft   <<<dim3(TCH, NN), dim3(256), 0, stream>>>(inp, ws);
    k_combine1<<<dim3(512),     dim3(256), 0, stream>>>(ws);
    k_l1p     <<<dim3(8, 4, 16),dim3(256), 0, stream>>>(W1, ws);
    k_l1c     <<<dim3(256),     dim3(256), 0, stream>>>(b1, ws);
    k_l2      <<<dim3(4096),    dim3(256), 0, stream>>>(W2, b2, ws);
    k_l3      <<<dim3(256),     dim3(256), 0, stream>>>(W3, b3, ws, out);
}

// Round 14
// 49.258 us; speedup vs baseline: 1.1357x; 1.1357x over previous
//
#include <hip/hip_runtime.h>
#include <math.h>

// Problem constants (fixed by harness)
#define NN   128
#define TT   1024
#define SS   1024
#define H1D  512
#define H2D  128
#define OUTD 8
#define KQN  8      // layer-1 split-K chunks

// NUFFT constants (validated R9/R11, absmax 0.0039): grid 2048, Gaussian w=12
#define MR    2048
#define WHALF 5
#define ALPHA 0.3702402f           // pi/sqrt(72)
#define BETA  6.35556e-6f          // pi^2/(ALPHA*MR^2)
#define DSCALE 0.3432943f          // sqrt(ALPHA/pi)
#define CSP   4                    // spread chunks per batch (256 pts each)

// ws layout in floats (~11.3 MB)
#define OFF_PART 0                          // [4 c][128 n][2048] float2 partial grids
#define OFF_FREQ (CSP*NN*MR*2)              // 2097152: freq [n][s]
#define OFF_P1   (OFF_FREQ + NN*SS)         // 2228224: P1 [8 kq][128 n][512 j]
#define OFF_H1   (OFF_P1 + KQN*NN*H1D)      // 2752512: h1 [n][512]
#define OFF_H2   (OFF_H1 + NN*H1D)          // 2818048: h2 [n][128] (end 2834432)

__device__ __forceinline__ float cos_rev(float r) { return __builtin_amdgcn_cosf(r); } // cos(2*pi*r)
__device__ __forceinline__ float sin_rev(float r) { return __builtin_amdgcn_sinf(r); } // sin(2*pi*r)

__device__ __forceinline__ float wave_sum(float v) {
#pragma unroll
    for (int off = 32; off > 0; off >>= 1) v += __shfl_xor(v, off, 64);
    return v;
}

// ---------------------------------------------------------------------------
// Kernel 1 (NEW): twist + Gaussian spread, partial grids (no global atomics).
// Block (c,n): 256 points t = c*256+tid -> 16KB LDS grid via ds_add_f32,
// then write grid to partial[c][n][*]. Math is R11-verbatim (validated).
// ---------------------------------------------------------------------------
__global__ __launch_bounds__(256) void k_spread(const float* __restrict__ inp,
                                                float* __restrict__ ws) {
    const int c   = blockIdx.x;    // 0..3
    const int n   = blockIdx.y;    // 0..127
    const int tid = threadIdx.x;   // 0..255

    __shared__ float2 G[MR];       // 16 KB
#pragma unroll
    for (int v = 0; v < MR / 256; ++v) G[v * 256 + tid] = make_float2(0.f, 0.f);

    float T[12];
#pragma unroll
    for (int k = 0; k < 12; ++k) {
        const int kk = k - WHALF;
        T[k] = __expf(-ALPHA * (float)(kk * kk));
    }
    __syncthreads();

    {
        const int t = c * 256 + tid;
        const float* p = inp + (size_t)(n * TT + t) * 3;
        const float x  = p[0];
        const float d  = p[2];
        const float df = d - floorf(d);            // exact for |d| < 2^23
        const float p512 = 512.0f * df;            // exact (pow2 scale)
        const float r512 = p512 - floorf(p512);
        const float cre = x * cos_rev(r512);
        const float cim = -x * sin_rev(r512);
        const float z  = df * 2048.0f;             // [0,2048)
        const int   j0 = (int)z;
        const float dl = z - (float)j0;
        float P = __expf(-ALPHA * dl * (dl + 10.0f));   // E1 * rho^-5
        const float R = __expf(2.0f * ALPHA * dl);      // rho
#pragma unroll
        for (int k = 0; k < 12; ++k) {
            const int gi = (j0 + k - WHALF) & (MR - 1);
            const float wk = P * T[k];
            atomicAdd(&G[gi].x, wk * cre);
            atomicAdd(&G[gi].y, wk * cim);
            P *= R;
        }
    }
    __syncthreads();

    float2* PART = (float2*)(ws + OFF_PART) + ((size_t)c * NN + n) * MR;
#pragma unroll
    for (int v = 0; v < MR / 256; ++v) PART[v * 256 + tid] = G[v * 256 + tid];
}

// ---------------------------------------------------------------------------
// Kernel 2 (NEW): sum 4 partial grids -> LDS; 2048-pt Stockham radix-2 FFT
// (R11 verbatim); deconvolve + magnitude -> freq[n][s]. 1024 threads.
// ---------------------------------------------------------------------------
__global__ __launch_bounds__(1024) void k_fft(float* __restrict__ ws) {
    const int n   = blockIdx.x;
    const int tid = threadIdx.x;   // 0..1023

    __shared__ float2 Ag[MR];      // 16 KB
    __shared__ float2 Bg[MR];      // 16 KB

    {
        const float2* PART = (const float2*)(ws + OFF_PART);
        float2 s0 = make_float2(0.f, 0.f), s1 = make_float2(0.f, 0.f);
#pragma unroll
        for (int c = 0; c < CSP; ++c) {
            const float2* P = PART + ((size_t)c * NN + n) * MR;
            const float2 a = P[tid];
            const float2 b = P[tid + 1024];
            s0.x += a.x; s0.y += a.y;
            s1.x += b.x; s1.y += b.y;
        }
        Ag[tid] = s0;
        Ag[tid + 1024] = s1;
    }
    __syncthreads();

    // Stockham radix-2 FFT, N=2048, 11 stages, 1 butterfly/thread (R11 verbatim)
    float2* src = Ag;
    float2* dst = Bg;
#pragma unroll
    for (int s = 0; s < 11; ++s) {
        const int   m     = 1 << s;
        const float inv2l = 1.0f / (float)(2048 >> s);
        const int tau = tid;
        const int j   = tau >> s;
        const float r = (float)j * inv2l;
        const float cv = cos_rev(r), sv = sin_rev(r);  // w = cv - i*sv
        const float2 a = src[tau];
        const float2 b = src[tau + 1024];
        const int o = tau + (tau & ~(m - 1));
        dst[o] = make_float2(a.x + b.x, a.y + b.y);
        const float dr = a.x - b.x, di = a.y - b.y;
        dst[o + m] = make_float2(fmaf(di, sv, dr * cv),
                                 fmaf(di, cv, -dr * sv));
        __syncthreads();
        float2* tmp = src; src = dst; dst = tmp;
    }

    // deconvolve + magnitude (R11 verbatim)
    {
        const int ss = tid;
        const int sp = ss - 512;
        const int bin = (ss + 1536) & (MR - 1);
        const float2 v = src[bin];
        const float D = DSCALE * __expf(BETA * (float)(sp * sp));
        ws[OFF_FREQ + (size_t)n * SS + ss] = sqrtf(fmaf(v.x, v.x, v.y * v.y)) * D;
    }
}

// ---------------------------------------------------------------------------
// Kernel 3: layer-1 split-K partial GEMM (R12 verbatim)
// ---------------------------------------------------------------------------
__global__ __launch_bounds__(256) void k_l1p(const float* __restrict__ W1,
                                             float* __restrict__ ws) {
    const int kq = blockIdx.x;   // 0..7   k-chunk of 128
    const int jq = blockIdx.y;   // 0..3   j-chunk of 128
    const int nb = blockIdx.z;   // 0..15  n-chunk of 8
    const int tid = threadIdx.x;

    __shared__ float4 Al[8][32];  // 8 n-rows x 128 k (as float4)
    const float4* FQ = (const float4*)(ws + OFF_FREQ);
    {
        const int row = tid >> 5, c4 = tid & 31;
        Al[row][c4] = FQ[(nb * 8 + row) * 256 + kq * 32 + c4];
    }
    __syncthreads();

    const int jl = tid & 127, ng = tid >> 7;
    const int j = jq * 128 + jl;
    const float4* W1v = (const float4*)W1;
    float a0 = 0.f, a1 = 0.f, a2 = 0.f, a3 = 0.f;
#pragma unroll 4
    for (int k4 = 0; k4 < 32; ++k4) {
        const float4 w  = W1v[(size_t)j * 256 + kq * 32 + k4];
        const float4 x0 = Al[ng * 4 + 0][k4];
        const float4 x1 = Al[ng * 4 + 1][k4];
        const float4 x2 = Al[ng * 4 + 2][k4];
        const float4 x3 = Al[ng * 4 + 3][k4];
        a0 = fmaf(x0.x, w.x, fmaf(x0.y, w.y, fmaf(x0.z, w.z, fmaf(x0.w, w.w, a0))));
        a1 = fmaf(x1.x, w.x, fmaf(x1.y, w.y, fmaf(x1.z, w.z, fmaf(x1.w, w.w, a1))));
        a2 = fmaf(x2.x, w.x, fmaf(x2.y, w.y, fmaf(x2.z, w.z, fmaf(x2.w, w.w, a2))));
        a3 = fmaf(x3.x, w.x, fmaf(x3.y, w.y, fmaf(x3.z, w.z, fmaf(x3.w, w.w, a3))));
    }
    float* P1 = ws + OFF_P1;
    const float acc[4] = {a0, a1, a2, a3};
#pragma unroll
    for (int i = 0; i < 4; ++i)
        P1[((size_t)(kq * NN + nb * 8 + ng * 4 + i)) * H1D + j] = acc[i];
}

// ---------------------------------------------------------------------------
// Kernel 4: combine layer-1 partials + bias + sigmoid -> h1 (R12 verbatim)
// ---------------------------------------------------------------------------
__global__ __launch_bounds__(256) void k_l1c(const float* __restrict__ b1,
                                             float* __restrict__ ws) {
    const int tid = blockIdx.x * 256 + threadIdx.x;   // = n*H1D + j
    const int j = tid & (H1D - 1);
    float s = b1[j];
#pragma unroll
    for (int kq = 0; kq < KQN; ++kq) s += ws[OFF_P1 + (size_t)kq * (NN * H1D) + tid];
    ws[OFF_H1 + tid] = 1.0f / (1.0f + __expf(-s));
}

// ---------------------------------------------------------------------------
// Kernel 5: layer-2, one wave per (n,j) (R12 verbatim)
// ---------------------------------------------------------------------------
__global__ __launch_bounds__(256) void k_l2(const float* __restrict__ W2,
                                            const float* __restrict__ b2,
                                            float* __restrict__ ws) {
    const int task = blockIdx.x * 4 + (threadIdx.x >> 6);   // 0..16383
    const int lane = threadIdx.x & 63;
    const int n = task >> 7, j = task & 127;

    const float4* W2v = (const float4*)W2 + (size_t)j * 128;
    const float4* H1v = (const float4*)(ws + OFF_H1) + (size_t)n * 128;
    const float4 wa = W2v[lane],      wb = W2v[64 + lane];
    const float4 ha = H1v[lane],      hb = H1v[64 + lane];
    float a = fmaf(wa.x, ha.x, fmaf(wa.y, ha.y, fmaf(wa.z, ha.z, wa.w * ha.w)));
    a = fmaf(wb.x, hb.x, fmaf(wb.y, hb.y, fmaf(wb.z, hb.z, fmaf(wb.w, hb.w, a))));
    a = wave_sum(a);
    if (lane == 0)
        ws[OFF_H2 + (size_t)n * H2D + j] = 1.0f / (1.0f + __expf(-(a + b2[j])));
}

// ---------------------------------------------------------------------------
// Kernel 6: layer-3, one wave per (n,j) (R12 verbatim)
// ---------------------------------------------------------------------------
__global__ __launch_bounds__(256) void k_l3(const float* __restrict__ W3,
                                            const float* __restrict__ b3,
                                            const float* __restrict__ ws,
                                            float* __restrict__ out) {
    const int task = blockIdx.x * 4 + (threadIdx.x >> 6);   // 0..1023
    const int lane = threadIdx.x & 63;
    const int n = task >> 3, j = task & 7;

    const float2 w = ((const float2*)W3)[j * 64 + lane];
    const float2 h = ((const float2*)(ws + OFF_H2 + (size_t)n * H2D))[lane];
    float a = fmaf(w.x, h.x, w.y * h.y);
    a = wave_sum(a);
    if (lane == 0) out[n * OUTD + j] = a + b3[j];
}

extern "C" void kernel_launch(void* const* d_in, const int* in_sizes, int n_in,
                              void* d_out, int out_size, void* d_ws, size_t ws_size,
                              hipStream_t stream) {
    (void)in_sizes; (void)n_in; (void)out_size; (void)ws_size;
    const float* inp = (const float*)d_in[0];
    const float* W1  = (const float*)d_in[1];
    const float* b1  = (const float*)d_in[2];
    const float* W2  = (const float*)d_in[3];
    const float* b2  = (const float*)d_in[4];
    const float* W3  = (const float*)d_in[5];
    const float* b3  = (const float*)d_in[6];
    float* out = (float*)d_out;
    float* ws  = (float*)d_ws;

    k_spread<<<dim3(CSP, NN), dim3(256),  0, stream>>>(inp, ws);
    k_fft   <<<dim3(NN),      dim3(1024), 0, stream>>>(ws);
    k_l1p   <<<dim3(8, 4, 16),dim3(256),  0, stream>>>(W1, ws);
    k_l1c   <<<dim3(256),     dim3(256),  0, stream>>>(b1, ws);
    k_l2    <<<dim3(4096),    dim3(256),  0, stream>>>(W2, b2, ws);
    k_l3    <<<dim3(256),     dim3(256),  0, stream>>>(W3, b3, ws, out);
}